// Round 17
// baseline (186.778 us; speedup 1.0000x reference)
//
#include <hip/hip_runtime.h>
#include <hip/hip_bf16.h>

typedef unsigned short u16;
typedef unsigned int u32;
typedef short bf16x8 __attribute__((ext_vector_type(8)));
typedef float f32x4 __attribute__((ext_vector_type(4)));

__device__ __forceinline__ u16 f2bf(float f) {
  union { float f; u32 i; } v; v.f = f;
  u32 x = v.i;
  x += 0x7fff + ((x >> 16) & 1);   // RNE
  return (u16)(x >> 16);
}
__device__ __forceinline__ u32 pack2(float a, float b) {
  return (u32)f2bf(a) | ((u32)f2bf(b) << 16);
}
// hardware v_cvt_pk_bf16_f32 (RNE)
__device__ __forceinline__ u32 cvtpk2(float a, float b) {
  __hip_bfloat162 t = __float22bfloat162_rn(float2{a, b});
  union { __hip_bfloat162 h; u32 u; } v; v.h = t; return v.u;
}
__device__ __forceinline__ float bf2f(u16 u) {
  union { u32 i; float f; } v; v.i = ((u32)u) << 16; return v.f;
}
__device__ __forceinline__ float fastrcp(float x) {
  float r;
  asm("v_rcp_f32 %0, %1" : "=v"(r) : "v"(x));
  return r;
}

// LDS-only barrier (validated R16): drain DS ops, leave VMEM in flight.
#define BAR_LDS() do { asm volatile("s_waitcnt lgkmcnt(0)" ::: "memory"); \
                       __builtin_amdgcn_s_barrier(); } while (0)

#define L2E 1.4426950408889634f

// ws layout (bytes):
//   bias  f32 [0, 65536)          ([h][q*64+k], pre-scaled by log2(e))
//   qkv_f bf16 [65536, 163840)    (384x128 fragment order; q rows pre-scaled by 32^-.5*log2e)
//   proj_f bf16 [163840, 196608)  (128x128 fragment order)
//   w1f   bf16 [196608, 327680)   (512x128 fragment order)
//   w2f   bf16 [327680, 458752)   (128x512 fragment order)
// Fragment order: tile(16 rows x 32 k) -> [tile][lane=((k>>3)&3)*16+(row&15)][k&7]

// ---------------- kernel 0: bias gather (log2-scaled) + fragment-order weight pack ----------------
__global__ void prep_kernel(const float* __restrict__ rpb, const int* __restrict__ rel,
                            const float* __restrict__ qkv_w, const float* __restrict__ proj_w,
                            const float* __restrict__ w1, const float* __restrict__ w2,
                            float* __restrict__ bias, u16* __restrict__ qkv_f,
                            u16* __restrict__ proj_f, u16* __restrict__ w1f,
                            u16* __restrict__ w2f) {
  const int bid = blockIdx.x;
  if (bid < 64) {
    const int idx = bid * 256 + threadIdx.x;   // 16384 bias entries: [h][q*64+k]
    const int h = idx >> 12, rm = idx & 4095;
    bias[idx] = rpb[rel[rm] * 4 + h] * L2E;
    return;
  }
  const int i4 = (bid - 64) * 256 + threadIdx.x;  // 49152 float4 groups
  const int e = i4 * 4;
  const float scale = 0.17677669529663687f * L2E; // 32^-0.5 * log2(e)
  float4 v; u16* dst;
  if (e < 49152) {            // qkv 384x128
    v = *(const float4*)(qkv_w + e);
    if (e < 16384) { v.x *= scale; v.y *= scale; v.z *= scale; v.w *= scale; }
    const int row = e >> 7, col = e & 127;
    const int tile = (row >> 4) * 4 + (col >> 5);
    const int lane = ((col >> 3) & 3) * 16 + (row & 15);
    dst = qkv_f + tile * 512 + lane * 8 + (col & 7);
  } else if (e < 65536) {     // proj 128x128
    const int le = e - 49152;
    v = *(const float4*)(proj_w + le);
    const int row = le >> 7, col = le & 127;
    const int tile = (row >> 4) * 4 + (col >> 5);
    const int lane = ((col >> 3) & 3) * 16 + (row & 15);
    dst = proj_f + tile * 512 + lane * 8 + (col & 7);
  } else if (e < 131072) {    // w1 512x128
    const int le = e - 65536;
    v = *(const float4*)(w1 + le);
    const int row = le >> 7, col = le & 127;
    const int tile = (row >> 4) * 4 + (col >> 5);
    const int lane = ((col >> 3) & 3) * 16 + (row & 15);
    dst = w1f + tile * 512 + lane * 8 + (col & 7);
  } else {                    // w2 128x512
    const int le = e - 131072;
    v = *(const float4*)(w2 + le);
    const int row = le >> 9, col = le & 511;
    const int tile = (row >> 4) * 16 + (col >> 5);
    const int lane = ((col >> 3) & 3) * 16 + (row & 15);
    dst = w2f + tile * 512 + lane * 8 + (col & 7);
  }
  *(uint2*)dst = make_uint2(pack2(v.x, v.y), pack2(v.z, v.w));
}

// ---------------- kernel 1: FUSED block, 53.2KB arena; Q and P register-resident ----------------
// LDS lifetimes: xw@0 | kb@17408 | vt@34816  (QKV phase, 53248B total)
//   Ob@0 (over xw, post-PV) | x1b@17408 (over kb, proj out, bf16) | xn@34816 (over vt)
//   h1c [64][68] dbuf @0/@8704 (over Ob, MLP phase)
__global__ __launch_bounds__(512, 4) void fused_kernel(
    const float* __restrict__ x, const u16* __restrict__ qkv_f,
    const u16* __restrict__ proj_f, const float* __restrict__ proj_b,
    const float* __restrict__ n1g, const float* __restrict__ n1b,
    const float* __restrict__ amask, const float* __restrict__ bias_t,
    const u16* __restrict__ w1f, const float* __restrict__ b1,
    const u16* __restrict__ w2f, const float* __restrict__ b2,
    const float* __restrict__ n2g, const float* __restrict__ n2b,
    float* __restrict__ out)
{
  __shared__ __align__(16) unsigned char lds[53248];
  __shared__ int srcIdx[64];
  u16* xw  = (u16*)(lds);           // [64][136] bf16
  u16* kb  = (u16*)(lds + 17408);   // [64][136]
  u16* vt  = (u16*)(lds + 34816);   // [128][72] channel-major V
  u16* Ob  = (u16*)(lds);           // [64][136] (over xw)
  u16* x1b = (u16*)(lds + 17408);   // [64][136] bf16 x1 (over kb)
  u16* xn  = (u16*)(lds + 34816);   // [64][136] (over vt)
  u16* h1c0 = (u16*)(lds);          // [64][68]  (over Ob)
  u16* h1c1 = (u16*)(lds + 8704);   // [64][68]

  const int tid = threadIdx.x;
  const int wv = tid >> 6, lane = tid & 63;
  const int l15 = lane & 15, lg = lane >> 4;
  const int hw = wv & 3;            // head / o-slice / c-slice
  const int half = wv >> 2;         // token half

  const int wIdx = blockIdx.x;
  const int bb = wIdx >> 9, ww = wIdx & 511;
  const int w0 = ww >> 6, w1i = (ww >> 3) & 7, w2i = ww & 7;
  const bool hasMask = (w0 == 7) || (w1i == 7) || (w2i == 7);

  // lane-exchange constants (D->B fragment): src lg_s = 2*(lg&1) + (w>>1)
  const int srcA = l15 + ((lg & 1) << 5);   // lg_s = 2(lg&1)
  const int srcB = srcA + 16;               // lg_s = 2(lg&1)+1
  const int selHi = lg >> 1;                // tile-select within pair

  // ---- A: LN1 + roll-gather into xw (8 threads per token) ----
  {
    const int tok = tid >> 3;
    const int qt = tid & 7;
    const int s0 = tok >> 4, s1 = (tok >> 2) & 3, s2 = tok & 3;
    const int p0 = (w0 * 4 + s0 + 2) & 31;
    const int p1 = (w1i * 4 + s1 + 2) & 31;
    const int p2 = (w2i * 4 + s2 + 2) & 31;
    const int src = (bb << 15) + (p0 << 10) + (p1 << 5) + p2;
    if (qt == 0) srcIdx[tok] = src;
    float v[16]; float s = 0.f, sq = 0.f;
    const float4* p4 = (const float4*)(x + src * 128 + qt * 16);
    #pragma unroll
    for (int i = 0; i < 4; ++i) {
      float4 u = p4[i];
      v[i * 4 + 0] = u.x; v[i * 4 + 1] = u.y; v[i * 4 + 2] = u.z; v[i * 4 + 3] = u.w;
      s += u.x + u.y + u.z + u.w;
      sq += u.x * u.x + u.y * u.y + u.z * u.z + u.w * u.w;
    }
    s  += __shfl_xor(s, 1);  s  += __shfl_xor(s, 2);  s  += __shfl_xor(s, 4);
    sq += __shfl_xor(sq, 1); sq += __shfl_xor(sq, 2); sq += __shfl_xor(sq, 4);
    const float mean = s * 0.0078125f;
    const float var  = sq * 0.0078125f - mean * mean;
    const float rstd = rsqrtf(var + 1e-5f);
    u16* dst = xw + tok * 136 + qt * 16;
    #pragma unroll
    for (int i = 0; i < 16; i += 2) {
      const int c = qt * 16 + i;
      float y0 = (v[i]     - mean) * rstd * n1g[c]     + n1b[c];
      float y1 = (v[i + 1] - mean) * rstd * n1g[c + 1] + n1b[c + 1];
      *(u32*)(dst + i) = cvtpk2(y0, y1);
    }
  }
  BAR_LDS();   // b1: xw ready

  const f32x4 zero4 = {0.f, 0.f, 0.f, 0.f};

  // hoist this wave's xw A/B-fragments: 8 x bf16x8 (xw reusable after all waves pass b2)
  bf16x8 xa[2][4];
  #pragma unroll
  for (int ti = 0; ti < 2; ++ti)
    #pragma unroll
    for (int ks = 0; ks < 4; ++ks)
      xa[ti][ks] = *(const bf16x8*)(xw + ((half * 2 + ti) * 16 + l15) * 136 + ks * 32 + lg * 8);

  // ---- B: QKV ----
  // Q: wave computes ITS head's o-tiles {2hw, 2hw+1}; D stays in regs (packed bf16)
  u32 pkq[2][2][2];   // [ti][Tq][m]
  #pragma unroll
  for (int Tq = 0; Tq < 2; ++Tq) {
    const u16* wp = qkv_f + ((2 * hw + Tq) * 4) * 512 + lane * 8;
    f32x4 acc[2] = {zero4, zero4};
    #pragma unroll
    for (int ks = 0; ks < 4; ++ks) {
      const bf16x8 bfr = *(const bf16x8*)(wp + ks * 512);
      acc[0] = __builtin_amdgcn_mfma_f32_16x16x32_bf16(bfr, xa[0][ks], acc[0], 0, 0, 0);
      acc[1] = __builtin_amdgcn_mfma_f32_16x16x32_bf16(bfr, xa[1][ks], acc[1], 0, 0, 0);
    }
    #pragma unroll
    for (int ti = 0; ti < 2; ++ti) {
      pkq[ti][Tq][0] = cvtpk2(acc[ti][0], acc[ti][1]);
      pkq[ti][Tq][1] = cvtpk2(acc[ti][2], acc[ti][3]);
    }
  }
  // K chunks (cc=2,3) -> kb
  #pragma unroll
  for (int cc = 2; cc < 4; ++cc) {
    const u16* wp = qkv_f + (cc * 4 + hw) * 4 * 512 + lane * 8;
    f32x4 acc[2] = {zero4, zero4};
    #pragma unroll
    for (int ks = 0; ks < 4; ++ks) {
      const bf16x8 bfr = *(const bf16x8*)(wp + ks * 512);
      acc[0] = __builtin_amdgcn_mfma_f32_16x16x32_bf16(bfr, xa[0][ks], acc[0], 0, 0, 0);
      acc[1] = __builtin_amdgcn_mfma_f32_16x16x32_bf16(bfr, xa[1][ks], acc[1], 0, 0, 0);
    }
    const int ob = (cc & 1) * 64 + hw * 16 + lg * 4;
    #pragma unroll
    for (int ti = 0; ti < 2; ++ti) {
      const int token = (half * 2 + ti) * 16 + l15;
      uint2 pk = make_uint2(cvtpk2(acc[ti][0], acc[ti][1]), cvtpk2(acc[ti][2], acc[ti][3]));
      *(uint2*)(kb + token * 136 + ob) = pk;
    }
  }
  // V chunks (cc=4,5) -> channel-major vt
  #pragma unroll
  for (int cc = 4; cc < 6; ++cc) {
    const u16* wp = qkv_f + (cc * 4 + hw) * 4 * 512 + lane * 8;
    f32x4 acc[2] = {zero4, zero4};
    #pragma unroll
    for (int ks = 0; ks < 4; ++ks) {
      const bf16x8 bfr = *(const bf16x8*)(wp + ks * 512);
      acc[0] = __builtin_amdgcn_mfma_f32_16x16x32_bf16(xa[0][ks], bfr, acc[0], 0, 0, 0);
      acc[1] = __builtin_amdgcn_mfma_f32_16x16x32_bf16(xa[1][ks], bfr, acc[1], 0, 0, 0);
    }
    const int cvch = (cc - 4) * 64 + hw * 16 + l15;   // v channel 0..127
    #pragma unroll
    for (int ti = 0; ti < 2; ++ti) {
      uint2 pk = make_uint2(cvtpk2(acc[ti][0], acc[ti][1]), cvtpk2(acc[ti][2], acc[ti][3]));
      *(uint2*)(vt + cvch * 72 + (half * 2 + ti) * 16 + lg * 4) = pk;
    }
  }
  BAR_LDS();   // b2: kb/vt ready (and all xa hoists done -> xw region reusable later)

  // ---- C: build Q B-fragments in-register (lane exchange), then QK^T = mfma(K_A, Q_B) ----
  // B word w (k = lg*8+2w..+1): src lane = srcA/srcB (w>>1), tile = selHi, payload word = w&1
  bf16x8 qB[2];
  #pragma unroll
  for (int ti = 0; ti < 2; ++ti) {
    u32 bw[4];
    #pragma unroll
    for (int w = 0; w < 4; ++w) {
      const int src = (w < 2) ? srcA : srcB;
      const int lo = __shfl((int)pkq[ti][0][w & 1], src, 64);
      const int hi = __shfl((int)pkq[ti][1][w & 1], src, 64);
      bw[w] = selHi ? (u32)hi : (u32)lo;
    }
    __builtin_memcpy(&qB[ti], bw, 16);
  }
  // scores: s[ti][tj] -> D col = qtok(l15, tile ti), row = ktok(tj*16 + lg*4 + r)
  f32x4 s[2][4];
  #pragma unroll
  for (int tj = 0; tj < 4; ++tj) {
    const bf16x8 kf = *(const bf16x8*)(kb + (tj * 16 + l15) * 136 + hw * 32 + lg * 8);
    s[0][tj] = __builtin_amdgcn_mfma_f32_16x16x32_bf16(kf, qB[0], zero4, 0, 0, 0);
    s[1][tj] = __builtin_amdgcn_mfma_f32_16x16x32_bf16(kf, qB[1], zero4, 0, 0, 0);
  }
  // bias [h][q*64+k]: float4 over k; mask likewise (boundary windows only)
  #pragma unroll
  for (int ti = 0; ti < 2; ++ti) {
    const int q = (half * 2 + ti) * 16 + l15;
    const float* bp = bias_t + hw * 4096 + q * 64;
    #pragma unroll
    for (int tj = 0; tj < 4; ++tj) {
      const float4 bt = *(const float4*)(bp + tj * 16 + lg * 4);
      s[ti][tj][0] += bt.x; s[ti][tj][1] += bt.y;
      s[ti][tj][2] += bt.z; s[ti][tj][3] += bt.w;
    }
  }
  if (hasMask) {
    #pragma unroll
    for (int ti = 0; ti < 2; ++ti) {
      const int q = (half * 2 + ti) * 16 + l15;
      const float* mp = amask + ww * 4096 + q * 64;
      #pragma unroll
      for (int tj = 0; tj < 4; ++tj) {
        const float4 m4 = *(const float4*)(mp + tj * 16 + lg * 4);
        s[ti][tj][0] = fmaf(m4.x, L2E, s[ti][tj][0]);
        s[ti][tj][1] = fmaf(m4.y, L2E, s[ti][tj][1]);
        s[ti][tj][2] = fmaf(m4.z, L2E, s[ti][tj][2]);
        s[ti][tj][3] = fmaf(m4.w, L2E, s[ti][tj][3]);
      }
    }
  }

  // ---- D: softmax (no-max, exp2) fully in-register; pack normalized P ----
  u32 pkp[2][4][2];   // [ti][tj][m]
  #pragma unroll
  for (int ti = 0; ti < 2; ++ti) {
    float sum = 0.f;
    #pragma unroll
    for (int tj = 0; tj < 4; ++tj)
      #pragma unroll
      for (int r = 0; r < 4; ++r) {
        s[ti][tj][r] = exp2f(s[ti][tj][r]);
        sum += s[ti][tj][r];
      }
    sum += __shfl_xor(sum, 16);
    sum += __shfl_xor(sum, 32);
    const float rcp = fastrcp(sum);
    #pragma unroll
    for (int tj = 0; tj < 4; ++tj) {
      pkp[ti][tj][0] = cvtpk2(s[ti][tj][0] * rcp, s[ti][tj][1] * rcp);
      pkp[ti][tj][1] = cvtpk2(s[ti][tj][2] * rcp, s[ti][tj][3] * rcp);
    }
  }

  // ---- E: PV = mfma(V_A, P_B); P B-frags via lane exchange; Ob write ----
  {
    f32x4 oacc[2][2] = {{zero4, zero4}, {zero4, zero4}};
    #pragma unroll
    for (int ks = 0; ks < 2; ++ks) {
      bf16x8 pB[2], vb[2];
      #pragma unroll
      for (int ti = 0; ti < 2; ++ti) {
        u32 bw[4];
        #pragma unroll
        for (int w = 0; w < 4; ++w) {
          const int src = (w < 2) ? srcA : srcB;
          const int lo = __shfl((int)pkp[ti][2 * ks][w & 1], src, 64);
          const int hi = __shfl((int)pkp[ti][2 * ks + 1][w & 1], src, 64);
          bw[w] = selHi ? (u32)hi : (u32)lo;
        }
        __builtin_memcpy(&pB[ti], bw, 16);
      }
      #pragma unroll
      for (int tj = 0; tj < 2; ++tj)
        vb[tj] = *(const bf16x8*)(vt + (hw * 32 + tj * 16 + l15) * 72 + ks * 32 + lg * 8);
      #pragma unroll
      for (int ti = 0; ti < 2; ++ti)
        #pragma unroll
        for (int tj = 0; tj < 2; ++tj)
          oacc[ti][tj] = __builtin_amdgcn_mfma_f32_16x16x32_bf16(vb[tj], pB[ti], oacc[ti][tj], 0, 0, 0);
    }
    #pragma unroll
    for (int ti = 0; ti < 2; ++ti)
      #pragma unroll
      for (int tj = 0; tj < 2; ++tj) {
        const int token = (half * 2 + ti) * 16 + l15;
        uint2 pk = make_uint2(cvtpk2(oacc[ti][tj][0], oacc[ti][tj][1]),
                              cvtpk2(oacc[ti][tj][2], oacc[ti][tj][3]));
        *(uint2*)(Ob + token * 136 + hw * 32 + tj * 16 + lg * 4) = pk;
      }
  }
  BAR_LDS();   // b3: Ob ready (kb/vt reads all done -> their regions reusable)

  // ---- F: proj SWAPPED; x1 = x + 0.5*(proj+pb) -> x1b (bf16, over kb) ----
  bf16x8 oafr[2][4];
  #pragma unroll
  for (int ti = 0; ti < 2; ++ti)
    #pragma unroll
    for (int ks = 0; ks < 4; ++ks)
      oafr[ti][ks] = *(const bf16x8*)(Ob + ((half * 2 + ti) * 16 + l15) * 136 + ks * 32 + lg * 8);
  #pragma unroll
  for (int cc = 0; cc < 2; ++cc) {
    const u16* wp = proj_f + (cc * 4 + hw) * 4 * 512 + lane * 8;
    f32x4 acc[2] = {zero4, zero4};
    #pragma unroll
    for (int ks = 0; ks < 4; ++ks) {
      const bf16x8 bfr = *(const bf16x8*)(wp + ks * 512);
      acc[0] = __builtin_amdgcn_mfma_f32_16x16x32_bf16(bfr, oafr[0][ks], acc[0], 0, 0, 0);
      acc[1] = __builtin_amdgcn_mfma_f32_16x16x32_bf16(bfr, oafr[1][ks], acc[1], 0, 0, 0);
    }
    const int cb = cc * 64 + hw * 16 + lg * 4;
    const float4 pb4 = *(const float4*)(proj_b + cb);
    #pragma unroll
    for (int ti = 0; ti < 2; ++ti) {
      const int token = (half * 2 + ti) * 16 + l15;
      float4 xr = *(const float4*)(x + srcIdx[token] * 128 + cb);
      xr.x += 0.5f * (acc[ti][0] + pb4.x);
      xr.y += 0.5f * (acc[ti][1] + pb4.y);
      xr.z += 0.5f * (acc[ti][2] + pb4.z);
      xr.w += 0.5f * (acc[ti][3] + pb4.w);
      *(uint2*)(x1b + token * 136 + cb) = make_uint2(cvtpk2(xr.x, xr.y), cvtpk2(xr.z, xr.w));
    }
  }
  BAR_LDS();   // b4: x1b ready; Ob reads (oafr) done -> region reusable

  // ---- G: LN2 over x1b (8 threads per token) -> xn (over vt) ----
  {
    const int tok = tid >> 3;
    const int qt = tid & 7;
    float v[16]; float s2 = 0.f, sq = 0.f;
    const uint4* p4 = (const uint4*)(x1b + tok * 136 + qt * 16);
    #pragma unroll
    for (int i = 0; i < 2; ++i) {
      uint4 u = p4[i];
      u32 w4[4] = {u.x, u.y, u.z, u.w};
      #pragma unroll
      for (int j = 0; j < 4; ++j) {
        float lo = bf2f((u16)(w4[j] & 0xffffu));
        float hi = bf2f((u16)(w4[j] >> 16));
        v[i * 8 + j * 2] = lo; v[i * 8 + j * 2 + 1] = hi;
        s2 += lo + hi; sq += lo * lo + hi * hi;
      }
    }
    s2 += __shfl_xor(s2, 1); s2 += __shfl_xor(s2, 2); s2 += __shfl_xor(s2, 4);
    sq += __shfl_xor(sq, 1); sq += __shfl_xor(sq, 2); sq += __shfl_xor(sq, 4);
    const float mean = s2 * 0.0078125f;
    const float var  = sq * 0.0078125f - mean * mean;
    const float rstd = rsqrtf(var + 1e-5f);
    u16* dst = xn + tok * 136 + qt * 16;
    #pragma unroll
    for (int i = 0; i < 16; i += 2) {
      const int c = qt * 16 + i;
      float y0 = (v[i]     - mean) * rstd * n2g[c]     + n2b[c];
      float y1 = (v[i + 1] - mean) * rstd * n2g[c + 1] + n2b[c + 1];
      *(u32*)(dst + i) = cvtpk2(y0, y1);
    }
  }
  BAR_LDS();   // b5: xn ready; h1c region (over Ob) free

  // ---- H: MLP: 8 oc chunks; wave (half, hw); h1c [64][68] dbuf ----
  f32x4 acc2[2][2] = {{zero4, zero4}, {zero4, zero4}};
  #pragma unroll 1
  for (int oc = 0; oc < 8; ++oc) {
    u16* h1c = (oc & 1) ? h1c1 : h1c0;
    // h1 SWAPPED mfma(W1, X): D col = token(l15), row = o_local(hw*16+lg*4+r)
    f32x4 a1[2] = {zero4, zero4};
    const u16* wp1 = w1f + (oc * 4 + hw) * 4 * 512 + lane * 8;
    #pragma unroll
    for (int ks = 0; ks < 4; ++ks) {
      const bf16x8 bfr = *(const bf16x8*)(wp1 + ks * 512);
      #pragma unroll
      for (int ti = 0; ti < 2; ++ti) {
        const bf16x8 afr = *(const bf16x8*)(xn + ((half * 2 + ti) * 16 + l15) * 136 + ks * 32 + lg * 8);
        a1[ti] = __builtin_amdgcn_mfma_f32_16x16x32_bf16(bfr, afr, a1[ti], 0, 0, 0);
      }
    }
    // prefetch w2 fragments for this oc (spans the barrier)
    bf16x8 w2r[2][2];
    #pragma unroll
    for (int tj = 0; tj < 2; ++tj)
      #pragma unroll
      for (int ks = 0; ks < 2; ++ks)
        w2r[tj][ks] = *(const bf16x8*)(w2f + (((hw * 2 + tj) * 16) + (oc * 2 + ks)) * 512 + lane * 8);

    const int olb = hw * 16 + lg * 4;             // 4 consecutive o per thread
    const float4 b14 = *(const float4*)(b1 + oc * 64 + olb);
    const float b1v[4] = {b14.x, b14.y, b14.z, b14.w};
    #pragma unroll
    for (int ti = 0; ti < 2; ++ti) {
      float g[4];
      #pragma unroll
      for (int r = 0; r < 4; ++r) {
        const float u = a1[ti][r] + b1v[r];
        // tanh-GELU via exp2: u * sigmoid(1.5957691*(u+0.044715u^3))
        const float t = u + 0.044715f * u * u * u;
        g[r] = u * fastrcp(1.0f + exp2f(-2.302207725f * t));
      }
      const int token = (half * 2 + ti) * 16 + l15;
      *(uint2*)(h1c + token * 68 + olb) = make_uint2(cvtpk2(g[0], g[1]), cvtpk2(g[2], g[3]));
    }
    BAR_LDS();   // h1c[oc&1] ready

    // h2 SWAPPED mfma(W2, H1): D col = token(l15), row = c(hw*32+tj*16+lg*4+r)
    #pragma unroll
    for (int ks = 0; ks < 2; ++ks) {
      bf16x8 afr[2];
      #pragma unroll
      for (int ti = 0; ti < 2; ++ti)
        afr[ti] = *(const bf16x8*)(h1c + ((half * 2 + ti) * 16 + l15) * 68 + ks * 32 + lg * 8);
      #pragma unroll
      for (int ti = 0; ti < 2; ++ti)
        #pragma unroll
        for (int tj = 0; tj < 2; ++tj)
          acc2[ti][tj] = __builtin_amdgcn_mfma_f32_16x16x32_bf16(w2r[tj][ks], afr[ti], acc2[ti][tj], 0, 0, 0);
    }
  }

  // ---- final epilogue: out = x1b + 0.5*(h2 + b2), single global write ----
  #pragma unroll
  for (int tj = 0; tj < 2; ++tj) {
    const int cb = hw * 32 + tj * 16 + lg * 4;
    const float4 b24 = *(const float4*)(b2 + cb);
    #pragma unroll
    for (int ti = 0; ti < 2; ++ti) {
      const int token = (half * 2 + ti) * 16 + l15;
      const int src = srcIdx[token];
      const uint2 xp = *(const uint2*)(x1b + token * 136 + cb);
      float4 xr;
      xr.x = bf2f((u16)(xp.x & 0xffffu)) + 0.5f * (acc2[ti][tj][0] + b24.x);
      xr.y = bf2f((u16)(xp.x >> 16))     + 0.5f * (acc2[ti][tj][1] + b24.y);
      xr.z = bf2f((u16)(xp.y & 0xffffu)) + 0.5f * (acc2[ti][tj][2] + b24.z);
      xr.w = bf2f((u16)(xp.y >> 16))     + 0.5f * (acc2[ti][tj][3] + b24.w);
      *(float4*)(out + src * 128 + cb) = xr;
    }
  }
}

extern "C" void kernel_launch(void* const* d_in, const int* in_sizes, int n_in,
                              void* d_out, int out_size, void* d_ws, size_t ws_size,
                              hipStream_t stream) {
  const float* x      = (const float*)d_in[0];
  const float* qkv_w  = (const float*)d_in[1];
  const float* rpb    = (const float*)d_in[2];
  const float* proj_w = (const float*)d_in[3];
  const float* proj_b = (const float*)d_in[4];
  const float* n1g    = (const float*)d_in[5];
  const float* n1b    = (const float*)d_in[6];
  const float* n2g    = (const float*)d_in[7];
  const float* n2b    = (const float*)d_in[8];
  const float* w1     = (const float*)d_in[9];
  const float* b1     = (const float*)d_in[10];
  const float* w2     = (const float*)d_in[11];
  const float* b2     = (const float*)d_in[12];
  const float* amask  = (const float*)d_in[13];
  const int*   rel    = (const int*)d_in[14];
  float* out  = (float*)d_out;

  unsigned char* ws = (unsigned char*)d_ws;
  float* bias_t = (float*)(ws);             // 64KB
  u16* qkv_f  = (u16*)(ws + 65536);         // 96KB
  u16* proj_f = (u16*)(ws + 163840);        // 32KB
  u16* w1f    = (u16*)(ws + 196608);        // 128KB
  u16* w2f    = (u16*)(ws + 327680);        // 128KB

  prep_kernel<<<256, 256, 0, stream>>>(rpb, rel, qkv_w, proj_w, w1, w2,
                                       bias_t, qkv_f, proj_f, w1f, w2f);
  fused_kernel<<<2048, 512, 0, stream>>>(x, qkv_f, proj_f, proj_b, n1g, n1b, amask, bias_t,
                                         w1f, b1, w2f, b2, n2g, n2b, out);
}

// Round 18
// 144.289 us; speedup vs baseline: 1.2945x; 1.2945x over previous
//
#include <hip/hip_runtime.h>
#include <hip/hip_bf16.h>

typedef unsigned short u16;
typedef unsigned int u32;
typedef short bf16x8 __attribute__((ext_vector_type(8)));
typedef float f32x4 __attribute__((ext_vector_type(4)));

__device__ __forceinline__ u16 f2bf(float f) {
  union { float f; u32 i; } v; v.f = f;
  u32 x = v.i;
  x += 0x7fff + ((x >> 16) & 1);   // RNE
  return (u16)(x >> 16);
}
__device__ __forceinline__ u32 pack2(float a, float b) {
  return (u32)f2bf(a) | ((u32)f2bf(b) << 16);
}
// hardware v_cvt_pk_bf16_f32 (RNE)
__device__ __forceinline__ u32 cvtpk2(float a, float b) {
  __hip_bfloat162 t = __float22bfloat162_rn(float2{a, b});
  union { __hip_bfloat162 h; u32 u; } v; v.h = t; return v.u;
}
__device__ __forceinline__ u16 f2bf1(float a) {   // single-op bf16 via cvt_pk
  return (u16)cvtpk2(a, a);
}
__device__ __forceinline__ float fastrcp(float x) {
  float r;
  asm("v_rcp_f32 %0, %1" : "=v"(r) : "v"(x));
  return r;
}

#define PRIO_HI() __builtin_amdgcn_s_setprio(1)
#define PRIO_LO() __builtin_amdgcn_s_setprio(0)

#define L2E 1.4426950408889634f

// ws layout (bytes):
//   bias_t f32 [0, 65536)         ([h][col][row], pre-scaled by log2(e))
//   qkv_f bf16 [65536, 163840)    (384x128 fragment order; q rows pre-scaled by 32^-.5*log2e)
//   proj_f bf16 [163840, 196608)  (128x128 fragment order)
//   w1f   bf16 [196608, 327680)   (512x128 fragment order)
//   w2f   bf16 [327680, 458752)   (128x512 fragment order)
// Fragment order: tile(16 rows x 32 k) -> [tile][lane=((k>>3)&3)*16+(row&15)][k&7]

// ---------------- kernel 0: bias gather (transposed, log2-scaled) + weight pack ----------------
__global__ void prep_kernel(const float* __restrict__ rpb, const int* __restrict__ rel,
                            const float* __restrict__ qkv_w, const float* __restrict__ proj_w,
                            const float* __restrict__ w1, const float* __restrict__ w2,
                            float* __restrict__ bias_t, u16* __restrict__ qkv_f,
                            u16* __restrict__ proj_f, u16* __restrict__ w1f,
                            u16* __restrict__ w2f) {
  const int bid = blockIdx.x;
  if (bid < 64) {
    const int idx = bid * 256 + threadIdx.x;   // 16384 bias entries
    const int h = idx >> 12, rm = idx & 4095;
    const int r = rm >> 6, c = rm & 63;
    bias_t[h * 4096 + c * 64 + r] = rpb[rel[rm] * 4 + h] * L2E;
    return;
  }
  const int i4 = (bid - 64) * 256 + threadIdx.x;  // 49152 float4 groups
  const int e = i4 * 4;
  const float scale = 0.17677669529663687f * L2E; // 32^-0.5 * log2(e)
  float4 v; u16* dst;
  if (e < 49152) {            // qkv 384x128
    v = *(const float4*)(qkv_w + e);
    if (e < 16384) { v.x *= scale; v.y *= scale; v.z *= scale; v.w *= scale; }
    const int row = e >> 7, col = e & 127;
    const int tile = (row >> 4) * 4 + (col >> 5);
    const int lane = ((col >> 3) & 3) * 16 + (row & 15);
    dst = qkv_f + tile * 512 + lane * 8 + (col & 7);
  } else if (e < 65536) {     // proj 128x128
    const int le = e - 49152;
    v = *(const float4*)(proj_w + le);
    const int row = le >> 7, col = le & 127;
    const int tile = (row >> 4) * 4 + (col >> 5);
    const int lane = ((col >> 3) & 3) * 16 + (row & 15);
    dst = proj_f + tile * 512 + lane * 8 + (col & 7);
  } else if (e < 131072) {    // w1 512x128
    const int le = e - 65536;
    v = *(const float4*)(w1 + le);
    const int row = le >> 7, col = le & 127;
    const int tile = (row >> 4) * 4 + (col >> 5);
    const int lane = ((col >> 3) & 3) * 16 + (row & 15);
    dst = w1f + tile * 512 + lane * 8 + (col & 7);
  } else {                    // w2 128x512
    const int le = e - 131072;
    v = *(const float4*)(w2 + le);
    const int row = le >> 9, col = le & 511;
    const int tile = (row >> 4) * 16 + (col >> 5);
    const int lane = ((col >> 3) & 3) * 16 + (row & 15);
    dst = w2f + tile * 512 + lane * 8 + (col & 7);
  }
  *(uint2*)dst = make_uint2(pack2(v.x, v.y), pack2(v.z, v.w));
}

// ---------------- kernel 1: FUSED block (R15 layout: 70.6KB LDS, 2 blocks/CU) ----------------
// R15 + s_setprio(1) around MFMA clusters (T5; 2 independently-phased blocks/CU)
__global__ __launch_bounds__(512, 4) void fused_kernel(
    const float* __restrict__ x, const u16* __restrict__ qkv_f,
    const u16* __restrict__ proj_f, const float* __restrict__ proj_b,
    const float* __restrict__ n1g, const float* __restrict__ n1b,
    const float* __restrict__ amask, const float* __restrict__ bias_t,
    const u16* __restrict__ w1f, const float* __restrict__ b1,
    const u16* __restrict__ w2f, const float* __restrict__ b2,
    const float* __restrict__ n2g, const float* __restrict__ n2b,
    float* __restrict__ out)
{
  __shared__ __align__(16) unsigned char lds[70656];
  __shared__ int srcIdx[64];
  u16* xw = (u16*)(lds);            // [64][136] bf16
  u16* qb = (u16*)(lds + 17408);    // [64][136]
  u16* kb = (u16*)(lds + 34816);    // [64][136]
  u16* vt = (u16*)(lds + 52224);    // [128][72] channel-major V
  unsigned char* Pb = lds;          // 8 x [32][128B] swizzled
  u16* Ob = kb;                     // [64][136]
  float* x1f = (float*)(lds);       // [64][132] f32 = 33792B (over dead Pb)
  u16* xn  = (u16*)(lds + 34816);   // [64][136] bf16 (over dead Ob)
  u16* h1c0 = (u16*)(lds + 52224);  // [64][72] (over dead vt)
  u16* h1c1 = (u16*)(lds + 61440);  // [64][72]

  const int tid = threadIdx.x;
  const int wv = tid >> 6, lane = tid & 63;
  const int l15 = lane & 15, lg = lane >> 4;
  const int hw = wv & 3;            // head / o-slice / c-slice
  const int half = wv >> 2;         // token half

  const int wIdx = blockIdx.x;
  const int bb = wIdx >> 9, ww = wIdx & 511;
  const int w0 = ww >> 6, w1i = (ww >> 3) & 7, w2i = ww & 7;
  const bool hasMask = (w0 == 7) || (w1i == 7) || (w2i == 7);

  // ---- A: LN1 + roll-gather into xw (8 threads per token) ----
  {
    const int tok = tid >> 3;
    const int qt = tid & 7;
    const int s0 = tok >> 4, s1 = (tok >> 2) & 3, s2 = tok & 3;
    const int p0 = (w0 * 4 + s0 + 2) & 31;
    const int p1 = (w1i * 4 + s1 + 2) & 31;
    const int p2 = (w2i * 4 + s2 + 2) & 31;
    const int src = (bb << 15) + (p0 << 10) + (p1 << 5) + p2;
    if (qt == 0) srcIdx[tok] = src;
    float v[16]; float s = 0.f, sq = 0.f;
    const float4* p4 = (const float4*)(x + src * 128 + qt * 16);
    #pragma unroll
    for (int i = 0; i < 4; ++i) {
      float4 u = p4[i];
      v[i * 4 + 0] = u.x; v[i * 4 + 1] = u.y; v[i * 4 + 2] = u.z; v[i * 4 + 3] = u.w;
      s += u.x + u.y + u.z + u.w;
      sq += u.x * u.x + u.y * u.y + u.z * u.z + u.w * u.w;
    }
    s  += __shfl_xor(s, 1);  s  += __shfl_xor(s, 2);  s  += __shfl_xor(s, 4);
    sq += __shfl_xor(sq, 1); sq += __shfl_xor(sq, 2); sq += __shfl_xor(sq, 4);
    const float mean = s * 0.0078125f;
    const float var  = sq * 0.0078125f - mean * mean;
    const float rstd = rsqrtf(var + 1e-5f);
    u16* dst = xw + tok * 136 + qt * 16;
    #pragma unroll
    for (int i = 0; i < 16; i += 2) {
      const int c = qt * 16 + i;
      float y0 = (v[i]     - mean) * rstd * n1g[c]     + n1b[c];
      float y1 = (v[i + 1] - mean) * rstd * n1g[c + 1] + n1b[c + 1];
      *(u32*)(dst + i) = cvtpk2(y0, y1);
    }
  }
  __syncthreads();   // b1: xw ready

  const f32x4 zero4 = {0.f, 0.f, 0.f, 0.f};

  // hoist this wave's xw A-fragments: 8 x bf16x8
  bf16x8 xa[2][4];
  #pragma unroll
  for (int ti = 0; ti < 2; ++ti)
    #pragma unroll
    for (int ks = 0; ks < 4; ++ks)
      xa[ti][ks] = *(const bf16x8*)(xw + ((half * 2 + ti) * 16 + l15) * 136 + ks * 32 + lg * 8);

  // ---- B: QKV (fragment-order weights) ----
  #pragma unroll
  for (int cc = 0; cc < 4; ++cc) {
    const u16* wp = qkv_f + (cc * 4 + hw) * 4 * 512 + lane * 8;
    f32x4 acc[2] = {zero4, zero4};
    PRIO_HI();
    #pragma unroll
    for (int ks = 0; ks < 4; ++ks) {
      const bf16x8 bfr = *(const bf16x8*)(wp + ks * 512);
      acc[0] = __builtin_amdgcn_mfma_f32_16x16x32_bf16(bfr, xa[0][ks], acc[0], 0, 0, 0);
      acc[1] = __builtin_amdgcn_mfma_f32_16x16x32_bf16(bfr, xa[1][ks], acc[1], 0, 0, 0);
    }
    PRIO_LO();
    u16* dstbuf = (cc < 2) ? qb : kb;
    const int ob = (cc & 1) * 64 + hw * 16 + lg * 4;
    #pragma unroll
    for (int ti = 0; ti < 2; ++ti) {
      const int token = (half * 2 + ti) * 16 + l15;
      uint2 pk = make_uint2(cvtpk2(acc[ti][0], acc[ti][1]), cvtpk2(acc[ti][2], acc[ti][3]));
      *(uint2*)(dstbuf + token * 136 + ob) = pk;
    }
  }
  #pragma unroll
  for (int cc = 4; cc < 6; ++cc) {
    const u16* wp = qkv_f + (cc * 4 + hw) * 4 * 512 + lane * 8;
    f32x4 acc[2] = {zero4, zero4};
    PRIO_HI();
    #pragma unroll
    for (int ks = 0; ks < 4; ++ks) {
      const bf16x8 bfr = *(const bf16x8*)(wp + ks * 512);
      acc[0] = __builtin_amdgcn_mfma_f32_16x16x32_bf16(xa[0][ks], bfr, acc[0], 0, 0, 0);
      acc[1] = __builtin_amdgcn_mfma_f32_16x16x32_bf16(xa[1][ks], bfr, acc[1], 0, 0, 0);
    }
    PRIO_LO();
    const int cvch = (cc - 4) * 64 + hw * 16 + l15;   // v channel 0..127
    #pragma unroll
    for (int ti = 0; ti < 2; ++ti) {
      uint2 pk = make_uint2(cvtpk2(acc[ti][0], acc[ti][1]), cvtpk2(acc[ti][2], acc[ti][3]));
      *(uint2*)(vt + cvch * 72 + (half * 2 + ti) * 16 + lg * 4) = pk;
    }
  }
  __syncthreads();   // b2: qb/kb/vt ready

  // ---- C: QK^T (log2 domain, scale pre-folded) ----
  f32x4 s[2][4];
  {
    bf16x8 qa[2];
    #pragma unroll
    for (int ti = 0; ti < 2; ++ti)
      qa[ti] = *(const bf16x8*)(qb + ((half * 2 + ti) * 16 + l15) * 136 + hw * 32 + lg * 8);
    PRIO_HI();
    #pragma unroll
    for (int tj = 0; tj < 4; ++tj) {
      const bf16x8 kf = *(const bf16x8*)(kb + (tj * 16 + l15) * 136 + hw * 32 + lg * 8);
      s[0][tj] = __builtin_amdgcn_mfma_f32_16x16x32_bf16(qa[0], kf, zero4, 0, 0, 0);
      s[1][tj] = __builtin_amdgcn_mfma_f32_16x16x32_bf16(qa[1], kf, zero4, 0, 0, 0);
    }
    PRIO_LO();
  }
  // bias (transposed table, float4 loads) + optional mask (boundary windows only)
  #pragma unroll
  for (int ti = 0; ti < 2; ++ti) {
    const int rowb = (half * 2 + ti) * 16 + lg * 4;
    #pragma unroll
    for (int tj = 0; tj < 4; ++tj) {
      const int col = tj * 16 + l15;
      const float4 bt = *(const float4*)(bias_t + hw * 4096 + col * 64 + rowb);
      s[ti][tj][0] += bt.x; s[ti][tj][1] += bt.y;
      s[ti][tj][2] += bt.z; s[ti][tj][3] += bt.w;
    }
  }
  if (hasMask) {
    #pragma unroll
    for (int ti = 0; ti < 2; ++ti) {
      #pragma unroll
      for (int r = 0; r < 4; ++r) {
        const int row = (half * 2 + ti) * 16 + lg * 4 + r;
        const float* mp = amask + ww * 4096 + row * 64;
        #pragma unroll
        for (int tj = 0; tj < 4; ++tj)
          s[ti][tj][r] = fmaf(mp[tj * 16 + l15], L2E, s[ti][tj][r]);
      }
    }
  }
  __syncthreads();   // b3: qb/kb reads done -> Pb region free

  // ---- prefetch residual x for proj (consumed after PV) ----
  float4 xres[2][2];
  #pragma unroll
  for (int cc = 0; cc < 2; ++cc) {
    const int cb = cc * 64 + hw * 16 + lg * 4;
    #pragma unroll
    for (int ti = 0; ti < 2; ++ti) {
      const int token = (half * 2 + ti) * 16 + l15;
      xres[cc][ti] = *(const float4*)(x + srcIdx[token] * 128 + cb);
    }
  }

  // ---- D: softmax (no-max, exp2) + P write (wave-private swizzled slice) ----
  unsigned char* ps = Pb + wv * 4096;   // [32][128B]
  #pragma unroll
  for (int ti = 0; ti < 2; ++ti) {
    #pragma unroll
    for (int r = 0; r < 4; ++r) {
      float e[4]; float sum = 0.f;
      #pragma unroll
      for (int tj = 0; tj < 4; ++tj) {
        e[tj] = exp2f(s[ti][tj][r]);
        sum += e[tj];
      }
      sum += __shfl_xor(sum, 1);
      sum += __shfl_xor(sum, 2);
      sum += __shfl_xor(sum, 4);
      sum += __shfl_xor(sum, 8);
      const float rcp = fastrcp(sum);
      const int row = ti * 16 + lg * 4 + r;          // slice-local row
      const int swz = (row & 7) << 4;
      #pragma unroll
      for (int tj = 0; tj < 4; ++tj) {
        const int byteoff = (row * 128 + (tj * 16 + l15) * 2) ^ swz;
        *(u16*)(ps + byteoff) = f2bf1(e[tj] * rcp);  // normalized P (1-op cvt)
      }
    }
  }
  // PV (wave-private ps; no barrier before reads)
  {
    f32x4 oacc[2][2] = {{zero4, zero4}, {zero4, zero4}};
    PRIO_HI();
    #pragma unroll
    for (int ks = 0; ks < 2; ++ks) {
      bf16x8 pa[2], vb[2];
      #pragma unroll
      for (int ti = 0; ti < 2; ++ti) {
        const int row = ti * 16 + l15;
        const int slot = ((ks * 4 + lg) ^ (row & 7)) << 4;
        pa[ti] = *(const bf16x8*)(ps + row * 128 + slot);
      }
      #pragma unroll
      for (int tj = 0; tj < 2; ++tj)
        vb[tj] = *(const bf16x8*)(vt + (hw * 32 + tj * 16 + l15) * 72 + ks * 32 + lg * 8);
      #pragma unroll
      for (int ti = 0; ti < 2; ++ti)
        #pragma unroll
        for (int tj = 0; tj < 2; ++tj)
          oacc[ti][tj] = __builtin_amdgcn_mfma_f32_16x16x32_bf16(vb[tj], pa[ti], oacc[ti][tj], 0, 0, 0);
    }
    PRIO_LO();
    #pragma unroll
    for (int ti = 0; ti < 2; ++ti)
      #pragma unroll
      for (int tj = 0; tj < 2; ++tj) {
        const int token = (half * 2 + ti) * 16 + l15;
        uint2 pk = make_uint2(cvtpk2(oacc[ti][tj][0], oacc[ti][tj][1]),
                              cvtpk2(oacc[ti][tj][2], oacc[ti][tj][3]));
        *(uint2*)(Ob + token * 136 + hw * 32 + tj * 16 + lg * 4) = pk;
      }
  }
  __syncthreads();   // b4: O visible; Pb dead -> x1f region free

  // ---- F: proj SWAPPED; x1 = x + 0.5*(proj+pb) -> x1f (LDS, f32) ----
  bf16x8 oafr[2][4];
  #pragma unroll
  for (int ti = 0; ti < 2; ++ti)
    #pragma unroll
    for (int ks = 0; ks < 4; ++ks)
      oafr[ti][ks] = *(const bf16x8*)(Ob + ((half * 2 + ti) * 16 + l15) * 136 + ks * 32 + lg * 8);
  #pragma unroll
  for (int cc = 0; cc < 2; ++cc) {
    const u16* wp = proj_f + (cc * 4 + hw) * 4 * 512 + lane * 8;
    f32x4 acc[2] = {zero4, zero4};
    PRIO_HI();
    #pragma unroll
    for (int ks = 0; ks < 4; ++ks) {
      const bf16x8 bfr = *(const bf16x8*)(wp + ks * 512);
      acc[0] = __builtin_amdgcn_mfma_f32_16x16x32_bf16(bfr, oafr[0][ks], acc[0], 0, 0, 0);
      acc[1] = __builtin_amdgcn_mfma_f32_16x16x32_bf16(bfr, oafr[1][ks], acc[1], 0, 0, 0);
    }
    PRIO_LO();
    const int cb = cc * 64 + hw * 16 + lg * 4;
    const float4 pb4 = *(const float4*)(proj_b + cb);
    #pragma unroll
    for (int ti = 0; ti < 2; ++ti) {
      const int token = (half * 2 + ti) * 16 + l15;
      float4 xr = xres[cc][ti];
      xr.x += 0.5f * (acc[ti][0] + pb4.x);
      xr.y += 0.5f * (acc[ti][1] + pb4.y);
      xr.z += 0.5f * (acc[ti][2] + pb4.z);
      xr.w += 0.5f * (acc[ti][3] + pb4.w);
      *(float4*)(x1f + token * 132 + cb) = xr;
    }
  }
  __syncthreads();   // b5: x1f complete; Ob dead -> xn region free

  // ---- G: LN2 over x1f (8 threads per token) -> xn bf16 ----
  {
    const int tok = tid >> 3;
    const int qt = tid & 7;
    float v[16]; float s2 = 0.f, sq = 0.f;
    const float4* p4 = (const float4*)(x1f + tok * 132 + qt * 16);
    #pragma unroll
    for (int i = 0; i < 4; ++i) {
      float4 u = p4[i];
      v[i * 4 + 0] = u.x; v[i * 4 + 1] = u.y; v[i * 4 + 2] = u.z; v[i * 4 + 3] = u.w;
      s2 += u.x + u.y + u.z + u.w;
      sq += u.x * u.x + u.y * u.y + u.z * u.z + u.w * u.w;
    }
    s2 += __shfl_xor(s2, 1); s2 += __shfl_xor(s2, 2); s2 += __shfl_xor(s2, 4);
    sq += __shfl_xor(sq, 1); sq += __shfl_xor(sq, 2); sq += __shfl_xor(sq, 4);
    const float mean = s2 * 0.0078125f;
    const float var  = sq * 0.0078125f - mean * mean;
    const float rstd = rsqrtf(var + 1e-5f);
    u16* dst = xn + tok * 136 + qt * 16;
    #pragma unroll
    for (int i = 0; i < 16; i += 2) {
      const int c = qt * 16 + i;
      float y0 = (v[i]     - mean) * rstd * n2g[c]     + n2b[c];
      float y1 = (v[i + 1] - mean) * rstd * n2g[c + 1] + n2b[c + 1];
      *(u32*)(dst + i) = cvtpk2(y0, y1);
    }
  }
  __syncthreads();   // b6: xn ready; vt dead -> h1c region free

  // ---- H: MLP: 8 oc chunks; wave (half, hw) ----
  f32x4 acc2[2][2] = {{zero4, zero4}, {zero4, zero4}};
  #pragma unroll 1
  for (int oc = 0; oc < 8; ++oc) {
    u16* h1c = (oc & 1) ? h1c1 : h1c0;
    // h1 SWAPPED mfma(W1, X): D col = token(l15), row = o_local(hw*16+lg*4+r)
    f32x4 a1[2] = {zero4, zero4};
    const u16* wp1 = w1f + (oc * 4 + hw) * 4 * 512 + lane * 8;
    PRIO_HI();
    #pragma unroll
    for (int ks = 0; ks < 4; ++ks) {
      const bf16x8 bfr = *(const bf16x8*)(wp1 + ks * 512);
      #pragma unroll
      for (int ti = 0; ti < 2; ++ti) {
        const bf16x8 afr = *(const bf16x8*)(xn + ((half * 2 + ti) * 16 + l15) * 136 + ks * 32 + lg * 8);
        a1[ti] = __builtin_amdgcn_mfma_f32_16x16x32_bf16(bfr, afr, a1[ti], 0, 0, 0);
      }
    }
    PRIO_LO();
    // prefetch w2 fragments for this oc (latency hides under GELU + barrier)
    bf16x8 w2r[2][2];
    #pragma unroll
    for (int tj = 0; tj < 2; ++tj)
      #pragma unroll
      for (int ks = 0; ks < 2; ++ks)
        w2r[tj][ks] = *(const bf16x8*)(w2f + (((hw * 2 + tj) * 16) + (oc * 2 + ks)) * 512 + lane * 8);

    const int olb = hw * 16 + lg * 4;             // 4 consecutive o per thread
    const float4 b14 = *(const float4*)(b1 + oc * 64 + olb);
    const float b1v[4] = {b14.x, b14.y, b14.z, b14.w};
    #pragma unroll
    for (int ti = 0; ti < 2; ++ti) {
      float g[4];
      #pragma unroll
      for (int r = 0; r < 4; ++r) {
        const float u = a1[ti][r] + b1v[r];
        // tanh-GELU via exp2: u * sigmoid(1.5957691*(u+0.044715u^3))
        const float t = u + 0.044715f * u * u * u;
        g[r] = u * fastrcp(1.0f + exp2f(-2.302207725f * t));
      }
      const int token = (half * 2 + ti) * 16 + l15;
      *(uint2*)(h1c + token * 72 + olb) = make_uint2(cvtpk2(g[0], g[1]), cvtpk2(g[2], g[3]));
    }
    __syncthreads();   // h1c[oc&1] ready

    // h2 SWAPPED mfma(W2, H1): D col = token(l15), row = c(hw*32+tj*16+lg*4+r)
    PRIO_HI();
    #pragma unroll
    for (int ks = 0; ks < 2; ++ks) {
      bf16x8 afr[2];
      #pragma unroll
      for (int ti = 0; ti < 2; ++ti)
        afr[ti] = *(const bf16x8*)(h1c + ((half * 2 + ti) * 16 + l15) * 72 + ks * 32 + lg * 8);
      #pragma unroll
      for (int ti = 0; ti < 2; ++ti)
        #pragma unroll
        for (int tj = 0; tj < 2; ++tj)
          acc2[ti][tj] = __builtin_amdgcn_mfma_f32_16x16x32_bf16(w2r[tj][ks], afr[ti], acc2[ti][tj], 0, 0, 0);
    }
    PRIO_LO();
  }

  // ---- final epilogue: out = x1f + 0.5*(h2 + b2), single global write ----
  #pragma unroll
  for (int tj = 0; tj < 2; ++tj) {
    const int cb = hw * 32 + tj * 16 + lg * 4;
    const float4 b24 = *(const float4*)(b2 + cb);
    #pragma unroll
    for (int ti = 0; ti < 2; ++ti) {
      const int token = (half * 2 + ti) * 16 + l15;
      const int src = srcIdx[token];
      float4 xr = *(const float4*)(x1f + token * 132 + cb);
      xr.x += 0.5f * (acc2[ti][tj][0] + b24.x);
      xr.y += 0.5f * (acc2[ti][tj][1] + b24.y);
      xr.z += 0.5f * (acc2[ti][tj][2] + b24.z);
      xr.w += 0.5f * (acc2[ti][tj][3] + b24.w);
      *(float4*)(out + src * 128 + cb) = xr;
    }
  }
}

extern "C" void kernel_launch(void* const* d_in, const int* in_sizes, int n_in,
                              void* d_out, int out_size, void* d_ws, size_t ws_size,
                              hipStream_t stream) {
  const float* x      = (const float*)d_in[0];
  const float* qkv_w  = (const float*)d_in[1];
  const float* rpb    = (const float*)d_in[2];
  const float* proj_w = (const float*)d_in[3];
  const float* proj_b = (const float*)d_in[4];
  const float* n1g    = (const float*)d_in[5];
  const float* n1b    = (const float*)d_in[6];
  const float* n2g    = (const float*)d_in[7];
  const float* n2b    = (const float*)d_in[8];
  const float* w1     = (const float*)d_in[9];
  const float* b1     = (const float*)d_in[10];
  const float* w2     = (const float*)d_in[11];
  const float* b2     = (const float*)d_in[12];
  const float* amask  = (const float*)d_in[13];
  const int*   rel    = (const int*)d_in[14];
  float* out  = (float*)d_out;

  unsigned char* ws = (unsigned char*)d_ws;
  float* bias_t = (float*)(ws);             // 64KB
  u16* qkv_f  = (u16*)(ws + 65536);         // 96KB
  u16* proj_f = (u16*)(ws + 163840);        // 32KB
  u16* w1f    = (u16*)(ws + 196608);        // 128KB
  u16* w2f    = (u16*)(ws + 327680);        // 128KB

  prep_kernel<<<256, 256, 0, stream>>>(rpb, rel, qkv_w, proj_w, w1, w2,
                                       bias_t, qkv_f, proj_f, w1f, w2f);
  fused_kernel<<<2048, 512, 0, stream>>>(x, qkv_f, proj_f, proj_b, n1g, n1b, amask, bias_t,
                                         w1f, b1, w2f, b2, n2g, n2b, out);
}

// Round 19
// 140.122 us; speedup vs baseline: 1.3330x; 1.0297x over previous
//
#include <hip/hip_runtime.h>
#include <hip/hip_bf16.h>

typedef unsigned short u16;
typedef unsigned int u32;
typedef short bf16x8 __attribute__((ext_vector_type(8)));
typedef float f32x4 __attribute__((ext_vector_type(4)));

__device__ __forceinline__ u16 f2bf(float f) {
  union { float f; u32 i; } v; v.f = f;
  u32 x = v.i;
  x += 0x7fff + ((x >> 16) & 1);   // RNE
  return (u16)(x >> 16);
}
__device__ __forceinline__ u32 pack2(float a, float b) {
  return (u32)f2bf(a) | ((u32)f2bf(b) << 16);
}
// hardware v_cvt_pk_bf16_f32 (RNE)
__device__ __forceinline__ u32 cvtpk2(float a, float b) {
  __hip_bfloat162 t = __float22bfloat162_rn(float2{a, b});
  union { __hip_bfloat162 h; u32 u; } v; v.h = t; return v.u;
}
__device__ __forceinline__ u16 f2bf1(float a) {   // single-op bf16 via cvt_pk
  return (u16)cvtpk2(a, a);
}
__device__ __forceinline__ float fastrcp(float x) {
  float r;
  asm("v_rcp_f32 %0, %1" : "=v"(r) : "v"(x));
  return r;
}

#define L2E 1.4426950408889634f

// ws layout (bytes):
//   bias_t f32 [0, 65536)         ([h][col][row], pre-scaled by log2(e))
//   qkv_f bf16 [65536, 163840)    (384x128 fragment order; q rows pre-scaled by 32^-.5*log2e)
//   proj_f bf16 [163840, 196608)  (128x128 fragment order)
//   w1f   bf16 [196608, 327680)   (512x128 fragment order)
//   w2f   bf16 [327680, 458752)   (128x512 fragment order)
// Fragment order: tile(16 rows x 32 k) -> [tile][lane=((k>>3)&3)*16+(row&15)][k&7]

// ---------------- kernel 0: bias gather (transposed, log2-scaled) + weight pack ----------------
__global__ void prep_kernel(const float* __restrict__ rpb, const int* __restrict__ rel,
                            const float* __restrict__ qkv_w, const float* __restrict__ proj_w,
                            const float* __restrict__ w1, const float* __restrict__ w2,
                            float* __restrict__ bias_t, u16* __restrict__ qkv_f,
                            u16* __restrict__ proj_f, u16* __restrict__ w1f,
                            u16* __restrict__ w2f) {
  const int bid = blockIdx.x;
  if (bid < 64) {
    const int idx = bid * 256 + threadIdx.x;   // 16384 bias entries
    const int h = idx >> 12, rm = idx & 4095;
    const int r = rm >> 6, c = rm & 63;
    bias_t[h * 4096 + c * 64 + r] = rpb[rel[rm] * 4 + h] * L2E;
    return;
  }
  const int i4 = (bid - 64) * 256 + threadIdx.x;  // 49152 float4 groups
  const int e = i4 * 4;
  const float scale = 0.17677669529663687f * L2E; // 32^-0.5 * log2(e)
  float4 v; u16* dst;
  if (e < 49152) {            // qkv 384x128
    v = *(const float4*)(qkv_w + e);
    if (e < 16384) { v.x *= scale; v.y *= scale; v.z *= scale; v.w *= scale; }
    const int row = e >> 7, col = e & 127;
    const int tile = (row >> 4) * 4 + (col >> 5);
    const int lane = ((col >> 3) & 3) * 16 + (row & 15);
    dst = qkv_f + tile * 512 + lane * 8 + (col & 7);
  } else if (e < 65536) {     // proj 128x128
    const int le = e - 49152;
    v = *(const float4*)(proj_w + le);
    const int row = le >> 7, col = le & 127;
    const int tile = (row >> 4) * 4 + (col >> 5);
    const int lane = ((col >> 3) & 3) * 16 + (row & 15);
    dst = proj_f + tile * 512 + lane * 8 + (col & 7);
  } else if (e < 131072) {    // w1 512x128
    const int le = e - 65536;
    v = *(const float4*)(w1 + le);
    const int row = le >> 7, col = le & 127;
    const int tile = (row >> 4) * 4 + (col >> 5);
    const int lane = ((col >> 3) & 3) * 16 + (row & 15);
    dst = w1f + tile * 512 + lane * 8 + (col & 7);
  } else {                    // w2 128x512
    const int le = e - 131072;
    v = *(const float4*)(w2 + le);
    const int row = le >> 9, col = le & 511;
    const int tile = (row >> 4) * 16 + (col >> 5);
    const int lane = ((col >> 3) & 3) * 16 + (row & 15);
    dst = w2f + tile * 512 + lane * 8 + (col & 7);
  }
  *(uint2*)dst = make_uint2(pack2(v.x, v.y), pack2(v.z, v.w));
}

// ---------------- kernel 1: FUSED block (70.6KB LDS, 2 blocks/CU) — best-known (R15) ----------------
__global__ __launch_bounds__(512, 4) void fused_kernel(
    const float* __restrict__ x, const u16* __restrict__ qkv_f,
    const u16* __restrict__ proj_f, const float* __restrict__ proj_b,
    const float* __restrict__ n1g, const float* __restrict__ n1b,
    const float* __restrict__ amask, const float* __restrict__ bias_t,
    const u16* __restrict__ w1f, const float* __restrict__ b1,
    const u16* __restrict__ w2f, const float* __restrict__ b2,
    const float* __restrict__ n2g, const float* __restrict__ n2b,
    float* __restrict__ out)
{
  __shared__ __align__(16) unsigned char lds[70656];
  __shared__ int srcIdx[64];
  u16* xw = (u16*)(lds);            // [64][136] bf16
  u16* qb = (u16*)(lds + 17408);    // [64][136]
  u16* kb = (u16*)(lds + 34816);    // [64][136]
  u16* vt = (u16*)(lds + 52224);    // [128][72] channel-major V
  unsigned char* Pb = lds;          // 8 x [32][128B] swizzled
  u16* Ob = kb;                     // [64][136]
  float* x1f = (float*)(lds);       // [64][132] f32 = 33792B (over dead Pb)
  u16* xn  = (u16*)(lds + 34816);   // [64][136] bf16 (over dead Ob)
  u16* h1c0 = (u16*)(lds + 52224);  // [64][72] (over dead vt)
  u16* h1c1 = (u16*)(lds + 61440);  // [64][72]

  const int tid = threadIdx.x;
  const int wv = tid >> 6, lane = tid & 63;
  const int l15 = lane & 15, lg = lane >> 4;
  const int hw = wv & 3;            // head / o-slice / c-slice
  const int half = wv >> 2;         // token half

  const int wIdx = blockIdx.x;
  const int bb = wIdx >> 9, ww = wIdx & 511;
  const int w0 = ww >> 6, w1i = (ww >> 3) & 7, w2i = ww & 7;
  const bool hasMask = (w0 == 7) || (w1i == 7) || (w2i == 7);

  // ---- A: LN1 + roll-gather into xw (8 threads per token) ----
  {
    const int tok = tid >> 3;
    const int qt = tid & 7;
    const int s0 = tok >> 4, s1 = (tok >> 2) & 3, s2 = tok & 3;
    const int p0 = (w0 * 4 + s0 + 2) & 31;
    const int p1 = (w1i * 4 + s1 + 2) & 31;
    const int p2 = (w2i * 4 + s2 + 2) & 31;
    const int src = (bb << 15) + (p0 << 10) + (p1 << 5) + p2;
    if (qt == 0) srcIdx[tok] = src;
    float v[16]; float s = 0.f, sq = 0.f;
    const float4* p4 = (const float4*)(x + src * 128 + qt * 16);
    #pragma unroll
    for (int i = 0; i < 4; ++i) {
      float4 u = p4[i];
      v[i * 4 + 0] = u.x; v[i * 4 + 1] = u.y; v[i * 4 + 2] = u.z; v[i * 4 + 3] = u.w;
      s += u.x + u.y + u.z + u.w;
      sq += u.x * u.x + u.y * u.y + u.z * u.z + u.w * u.w;
    }
    s  += __shfl_xor(s, 1);  s  += __shfl_xor(s, 2);  s  += __shfl_xor(s, 4);
    sq += __shfl_xor(sq, 1); sq += __shfl_xor(sq, 2); sq += __shfl_xor(sq, 4);
    const float mean = s * 0.0078125f;
    const float var  = sq * 0.0078125f - mean * mean;
    const float rstd = rsqrtf(var + 1e-5f);
    u16* dst = xw + tok * 136 + qt * 16;
    #pragma unroll
    for (int i = 0; i < 16; i += 2) {
      const int c = qt * 16 + i;
      float y0 = (v[i]     - mean) * rstd * n1g[c]     + n1b[c];
      float y1 = (v[i + 1] - mean) * rstd * n1g[c + 1] + n1b[c + 1];
      *(u32*)(dst + i) = cvtpk2(y0, y1);
    }
  }
  __syncthreads();   // b1: xw ready

  const f32x4 zero4 = {0.f, 0.f, 0.f, 0.f};

  // hoist this wave's xw A-fragments: 8 x bf16x8
  bf16x8 xa[2][4];
  #pragma unroll
  for (int ti = 0; ti < 2; ++ti)
    #pragma unroll
    for (int ks = 0; ks < 4; ++ks)
      xa[ti][ks] = *(const bf16x8*)(xw + ((half * 2 + ti) * 16 + l15) * 136 + ks * 32 + lg * 8);

  // ---- B: QKV (fragment-order weights) ----
  #pragma unroll
  for (int cc = 0; cc < 4; ++cc) {
    const u16* wp = qkv_f + (cc * 4 + hw) * 4 * 512 + lane * 8;
    f32x4 acc[2] = {zero4, zero4};
    #pragma unroll
    for (int ks = 0; ks < 4; ++ks) {
      const bf16x8 bfr = *(const bf16x8*)(wp + ks * 512);
      acc[0] = __builtin_amdgcn_mfma_f32_16x16x32_bf16(bfr, xa[0][ks], acc[0], 0, 0, 0);
      acc[1] = __builtin_amdgcn_mfma_f32_16x16x32_bf16(bfr, xa[1][ks], acc[1], 0, 0, 0);
    }
    u16* dstbuf = (cc < 2) ? qb : kb;
    const int ob = (cc & 1) * 64 + hw * 16 + lg * 4;
    #pragma unroll
    for (int ti = 0; ti < 2; ++ti) {
      const int token = (half * 2 + ti) * 16 + l15;
      uint2 pk = make_uint2(cvtpk2(acc[ti][0], acc[ti][1]), cvtpk2(acc[ti][2], acc[ti][3]));
      *(uint2*)(dstbuf + token * 136 + ob) = pk;
    }
  }
  #pragma unroll
  for (int cc = 4; cc < 6; ++cc) {
    const u16* wp = qkv_f + (cc * 4 + hw) * 4 * 512 + lane * 8;
    f32x4 acc[2] = {zero4, zero4};
    #pragma unroll
    for (int ks = 0; ks < 4; ++ks) {
      const bf16x8 bfr = *(const bf16x8*)(wp + ks * 512);
      acc[0] = __builtin_amdgcn_mfma_f32_16x16x32_bf16(xa[0][ks], bfr, acc[0], 0, 0, 0);
      acc[1] = __builtin_amdgcn_mfma_f32_16x16x32_bf16(xa[1][ks], bfr, acc[1], 0, 0, 0);
    }
    const int cvch = (cc - 4) * 64 + hw * 16 + l15;   // v channel 0..127
    #pragma unroll
    for (int ti = 0; ti < 2; ++ti) {
      uint2 pk = make_uint2(cvtpk2(acc[ti][0], acc[ti][1]), cvtpk2(acc[ti][2], acc[ti][3]));
      *(uint2*)(vt + cvch * 72 + (half * 2 + ti) * 16 + lg * 4) = pk;
    }
  }
  __syncthreads();   // b2: qb/kb/vt ready

  // ---- C: QK^T (log2 domain, scale pre-folded) ----
  f32x4 s[2][4];
  {
    bf16x8 qa[2];
    #pragma unroll
    for (int ti = 0; ti < 2; ++ti)
      qa[ti] = *(const bf16x8*)(qb + ((half * 2 + ti) * 16 + l15) * 136 + hw * 32 + lg * 8);
    #pragma unroll
    for (int tj = 0; tj < 4; ++tj) {
      const bf16x8 kf = *(const bf16x8*)(kb + (tj * 16 + l15) * 136 + hw * 32 + lg * 8);
      s[0][tj] = __builtin_amdgcn_mfma_f32_16x16x32_bf16(qa[0], kf, zero4, 0, 0, 0);
      s[1][tj] = __builtin_amdgcn_mfma_f32_16x16x32_bf16(qa[1], kf, zero4, 0, 0, 0);
    }
  }
  // bias (transposed table, float4 loads) + optional mask (boundary windows only)
  #pragma unroll
  for (int ti = 0; ti < 2; ++ti) {
    const int rowb = (half * 2 + ti) * 16 + lg * 4;
    #pragma unroll
    for (int tj = 0; tj < 4; ++tj) {
      const int col = tj * 16 + l15;
      const float4 bt = *(const float4*)(bias_t + hw * 4096 + col * 64 + rowb);
      s[ti][tj][0] += bt.x; s[ti][tj][1] += bt.y;
      s[ti][tj][2] += bt.z; s[ti][tj][3] += bt.w;
    }
  }
  if (hasMask) {
    #pragma unroll
    for (int ti = 0; ti < 2; ++ti) {
      #pragma unroll
      for (int r = 0; r < 4; ++r) {
        const int row = (half * 2 + ti) * 16 + lg * 4 + r;
        const float* mp = amask + ww * 4096 + row * 64;
        #pragma unroll
        for (int tj = 0; tj < 4; ++tj)
          s[ti][tj][r] = fmaf(mp[tj * 16 + l15], L2E, s[ti][tj][r]);
      }
    }
  }
  __syncthreads();   // b3: qb/kb reads done -> Pb region free

  // ---- prefetch residual x for proj (consumed after PV; latency hides under softmax+PV) ----
  float4 xres[2][2];
  #pragma unroll
  for (int cc = 0; cc < 2; ++cc) {
    const int cb = cc * 64 + hw * 16 + lg * 4;
    #pragma unroll
    for (int ti = 0; ti < 2; ++ti) {
      const int token = (half * 2 + ti) * 16 + l15;
      xres[cc][ti] = *(const float4*)(x + srcIdx[token] * 128 + cb);
    }
  }

  // ---- D: softmax (no-max, exp2) + P write (wave-private swizzled slice) ----
  unsigned char* ps = Pb + wv * 4096;   // [32][128B]
  #pragma unroll
  for (int ti = 0; ti < 2; ++ti) {
    #pragma unroll
    for (int r = 0; r < 4; ++r) {
      float e[4]; float sum = 0.f;
      #pragma unroll
      for (int tj = 0; tj < 4; ++tj) {
        e[tj] = exp2f(s[ti][tj][r]);
        sum += e[tj];
      }
      sum += __shfl_xor(sum, 1);
      sum += __shfl_xor(sum, 2);
      sum += __shfl_xor(sum, 4);
      sum += __shfl_xor(sum, 8);
      const float rcp = fastrcp(sum);
      const int row = ti * 16 + lg * 4 + r;          // slice-local row
      const int swz = (row & 7) << 4;
      #pragma unroll
      for (int tj = 0; tj < 4; ++tj) {
        const int byteoff = (row * 128 + (tj * 16 + l15) * 2) ^ swz;
        *(u16*)(ps + byteoff) = f2bf1(e[tj] * rcp);  // normalized P (1-op cvt)
      }
    }
  }
  // PV (wave-private ps; no barrier before reads)
  {
    f32x4 oacc[2][2] = {{zero4, zero4}, {zero4, zero4}};
    #pragma unroll
    for (int ks = 0; ks < 2; ++ks) {
      bf16x8 pa[2], vb[2];
      #pragma unroll
      for (int ti = 0; ti < 2; ++ti) {
        const int row = ti * 16 + l15;
        const int slot = ((ks * 4 + lg) ^ (row & 7)) << 4;
        pa[ti] = *(const bf16x8*)(ps + row * 128 + slot);
      }
      #pragma unroll
      for (int tj = 0; tj < 2; ++tj)
        vb[tj] = *(const bf16x8*)(vt + (hw * 32 + tj * 16 + l15) * 72 + ks * 32 + lg * 8);
      #pragma unroll
      for (int ti = 0; ti < 2; ++ti)
        #pragma unroll
        for (int tj = 0; tj < 2; ++tj)
          oacc[ti][tj] = __builtin_amdgcn_mfma_f32_16x16x32_bf16(vb[tj], pa[ti], oacc[ti][tj], 0, 0, 0);
    }
    #pragma unroll
    for (int ti = 0; ti < 2; ++ti)
      #pragma unroll
      for (int tj = 0; tj < 2; ++tj) {
        const int token = (half * 2 + ti) * 16 + l15;
        uint2 pk = make_uint2(cvtpk2(oacc[ti][tj][0], oacc[ti][tj][1]),
                              cvtpk2(oacc[ti][tj][2], oacc[ti][tj][3]));
        *(uint2*)(Ob + token * 136 + hw * 32 + tj * 16 + lg * 4) = pk;
      }
  }
  __syncthreads();   // b4: O visible; Pb dead -> x1f region free

  // ---- F: proj SWAPPED; x1 = x + 0.5*(proj+pb) -> x1f (LDS, f32) ----
  bf16x8 oafr[2][4];
  #pragma unroll
  for (int ti = 0; ti < 2; ++ti)
    #pragma unroll
    for (int ks = 0; ks < 4; ++ks)
      oafr[ti][ks] = *(const bf16x8*)(Ob + ((half * 2 + ti) * 16 + l15) * 136 + ks * 32 + lg * 8);
  #pragma unroll
  for (int cc = 0; cc < 2; ++cc) {
    const u16* wp = proj_f + (cc * 4 + hw) * 4 * 512 + lane * 8;
    f32x4 acc[2] = {zero4, zero4};
    #pragma unroll
    for (int ks = 0; ks < 4; ++ks) {
      const bf16x8 bfr = *(const bf16x8*)(wp + ks * 512);
      acc[0] = __builtin_amdgcn_mfma_f32_16x16x32_bf16(bfr, oafr[0][ks], acc[0], 0, 0, 0);
      acc[1] = __builtin_amdgcn_mfma_f32_16x16x32_bf16(bfr, oafr[1][ks], acc[1], 0, 0, 0);
    }
    const int cb = cc * 64 + hw * 16 + lg * 4;
    const float4 pb4 = *(const float4*)(proj_b + cb);
    #pragma unroll
    for (int ti = 0; ti < 2; ++ti) {
      const int token = (half * 2 + ti) * 16 + l15;
      float4 xr = xres[cc][ti];
      xr.x += 0.5f * (acc[ti][0] + pb4.x);
      xr.y += 0.5f * (acc[ti][1] + pb4.y);
      xr.z += 0.5f * (acc[ti][2] + pb4.z);
      xr.w += 0.5f * (acc[ti][3] + pb4.w);
      *(float4*)(x1f + token * 132 + cb) = xr;
    }
  }
  __syncthreads();   // b5: x1f complete; Ob dead -> xn region free

  // ---- G: LN2 over x1f (8 threads per token) -> xn bf16 ----
  {
    const int tok = tid >> 3;
    const int qt = tid & 7;
    float v[16]; float s2 = 0.f, sq = 0.f;
    const float4* p4 = (const float4*)(x1f + tok * 132 + qt * 16);
    #pragma unroll
    for (int i = 0; i < 4; ++i) {
      float4 u = p4[i];
      v[i * 4 + 0] = u.x; v[i * 4 + 1] = u.y; v[i * 4 + 2] = u.z; v[i * 4 + 3] = u.w;
      s2 += u.x + u.y + u.z + u.w;
      sq += u.x * u.x + u.y * u.y + u.z * u.z + u.w * u.w;
    }
    s2 += __shfl_xor(s2, 1); s2 += __shfl_xor(s2, 2); s2 += __shfl_xor(s2, 4);
    sq += __shfl_xor(sq, 1); sq += __shfl_xor(sq, 2); sq += __shfl_xor(sq, 4);
    const float mean = s2 * 0.0078125f;
    const float var  = sq * 0.0078125f - mean * mean;
    const float rstd = rsqrtf(var + 1e-5f);
    u16* dst = xn + tok * 136 + qt * 16;
    #pragma unroll
    for (int i = 0; i < 16; i += 2) {
      const int c = qt * 16 + i;
      float y0 = (v[i]     - mean) * rstd * n2g[c]     + n2b[c];
      float y1 = (v[i + 1] - mean) * rstd * n2g[c + 1] + n2b[c + 1];
      *(u32*)(dst + i) = cvtpk2(y0, y1);
    }
  }
  __syncthreads();   // b6: xn ready; vt dead -> h1c region free

  // ---- H: MLP: 8 oc chunks; wave (half, hw) ----
  f32x4 acc2[2][2] = {{zero4, zero4}, {zero4, zero4}};
  #pragma unroll 1
  for (int oc = 0; oc < 8; ++oc) {
    u16* h1c = (oc & 1) ? h1c1 : h1c0;
    // h1 SWAPPED mfma(W1, X): D col = token(l15), row = o_local(hw*16+lg*4+r)
    f32x4 a1[2] = {zero4, zero4};
    const u16* wp1 = w1f + (oc * 4 + hw) * 4 * 512 + lane * 8;
    #pragma unroll
    for (int ks = 0; ks < 4; ++ks) {
      const bf16x8 bfr = *(const bf16x8*)(wp1 + ks * 512);
      #pragma unroll
      for (int ti = 0; ti < 2; ++ti) {
        const bf16x8 afr = *(const bf16x8*)(xn + ((half * 2 + ti) * 16 + l15) * 136 + ks * 32 + lg * 8);
        a1[ti] = __builtin_amdgcn_mfma_f32_16x16x32_bf16(bfr, afr, a1[ti], 0, 0, 0);
      }
    }
    // prefetch w2 fragments for this oc (latency hides under GELU + barrier)
    bf16x8 w2r[2][2];
    #pragma unroll
    for (int tj = 0; tj < 2; ++tj)
      #pragma unroll
      for (int ks = 0; ks < 2; ++ks)
        w2r[tj][ks] = *(const bf16x8*)(w2f + (((hw * 2 + tj) * 16) + (oc * 2 + ks)) * 512 + lane * 8);

    const int olb = hw * 16 + lg * 4;             // 4 consecutive o per thread
    const float4 b14 = *(const float4*)(b1 + oc * 64 + olb);
    const float b1v[4] = {b14.x, b14.y, b14.z, b14.w};
    #pragma unroll
    for (int ti = 0; ti < 2; ++ti) {
      float g[4];
      #pragma unroll
      for (int r = 0; r < 4; ++r) {
        const float u = a1[ti][r] + b1v[r];
        // tanh-GELU via exp2: u * sigmoid(1.5957691*(u+0.044715u^3))
        const float t = u + 0.044715f * u * u * u;
        g[r] = u * fastrcp(1.0f + exp2f(-2.302207725f * t));
      }
      const int token = (half * 2 + ti) * 16 + l15;
      *(uint2*)(h1c + token * 72 + olb) = make_uint2(cvtpk2(g[0], g[1]), cvtpk2(g[2], g[3]));
    }
    __syncthreads();   // h1c[oc&1] ready

    // h2 SWAPPED mfma(W2, H1): D col = token(l15), row = c(hw*32+tj*16+lg*4+r)
    #pragma unroll
    for (int ks = 0; ks < 2; ++ks) {
      bf16x8 afr[2];
      #pragma unroll
      for (int ti = 0; ti < 2; ++ti)
        afr[ti] = *(const bf16x8*)(h1c + ((half * 2 + ti) * 16 + l15) * 72 + ks * 32 + lg * 8);
      #pragma unroll
      for (int ti = 0; ti < 2; ++ti)
        #pragma unroll
        for (int tj = 0; tj < 2; ++tj)
          acc2[ti][tj] = __builtin_amdgcn_mfma_f32_16x16x32_bf16(w2r[tj][ks], afr[ti], acc2[ti][tj], 0, 0, 0);
    }
  }

  // ---- final epilogue: out = x1f + 0.5*(h2 + b2), single global write ----
  #pragma unroll
  for (int tj = 0; tj < 2; ++tj) {
    const int cb = hw * 32 + tj * 16 + lg * 4;
    const float4 b24 = *(const float4*)(b2 + cb);
    #pragma unroll
    for (int ti = 0; ti < 2; ++ti) {
      const int token = (half * 2 + ti) * 16 + l15;
      const int src = srcIdx[token];
      float4 xr = *(const float4*)(x1f + token * 132 + cb);
      xr.x += 0.5f * (acc2[ti][tj][0] + b24.x);
      xr.y += 0.5f * (acc2[ti][tj][1] + b24.y);
      xr.z += 0.5f * (acc2[ti][tj][2] + b24.z);
      xr.w += 0.5f * (acc2[ti][tj][3] + b24.w);
      *(float4*)(out + src * 128 + cb) = xr;
    }
  }
}

extern "C" void kernel_launch(void* const* d_in, const int* in_sizes, int n_in,
                              void* d_out, int out_size, void* d_ws, size_t ws_size,
                              hipStream_t stream) {
  const float* x      = (const float*)d_in[0];
  const float* qkv_w  = (const float*)d_in[1];
  const float* rpb    = (const float*)d_in[2];
  const float* proj_w = (const float*)d_in[3];
  const float* proj_b = (const float*)d_in[4];
  const float* n1g    = (const float*)d_in[5];
  const float* n1b    = (const float*)d_in[6];
  const float* n2g    = (const float*)d_in[7];
  const float* n2b    = (const float*)d_in[8];
  const float* w1     = (const float*)d_in[9];
  const float* b1     = (const float*)d_in[10];
  const float* w2     = (const float*)d_in[11];
  const float* b2     = (const float*)d_in[12];
  const float* amask  = (const float*)d_in[13];
  const int*   rel    = (const int*)d_in[14];
  float* out  = (float*)d_out;

  unsigned char* ws = (unsigned char*)d_ws;
  float* bias_t = (float*)(ws);             // 64KB
  u16* qkv_f  = (u16*)(ws + 65536);         // 96KB
  u16* proj_f = (u16*)(ws + 163840);        // 32KB
  u16* w1f    = (u16*)(ws + 196608);        // 128KB
  u16* w2f    = (u16*)(ws + 327680);        // 128KB

  prep_kernel<<<256, 256, 0, stream>>>(rpb, rel, qkv_w, proj_w, w1, w2,
                                       bias_t, qkv_f, proj_f, w1f, w2f);
  fused_kernel<<<2048, 512, 0, stream>>>(x, qkv_f, proj_f, proj_b, n1g, n1b, amask, bias_t,
                                         w1f, b1, w2f, b2, n2g, n2b, out);
}